// Round 1
// baseline (3253.345 us; speedup 1.0000x reference)
//
#include <hip/hip_runtime.h>

#define NPTS 40000
#define PPB  10000
#define CIN  256
#define COUT 256
#define KKP  15
#define NNB  16
#define IH   64
#define IW   2048
#define KPINV (1.0f/1.2f)

// ws layout (floats)
#define WS_FEATS 0
#define WS_WALL  (NPTS*CIN)                   // 10,240,000
#define WS_SUMS  (WS_WALL + NPTS*KKP*NNB)     // 19,840,000
// sums: [0:256) sum, [256:512) sumsq, [512:768) scale, [768:1024) shift
// total ws use: 19,841,024 floats = 79.4 MB

__global__ void k_zero(float* __restrict__ p) {
  p[blockIdx.x*256 + threadIdx.x] = 0.f;
}

// ---- bilinear grid sample, border clamp, align_corners=False ----
__global__ void k_feats(const float* __restrict__ x, const float* __restrict__ px,
                        const float* __restrict__ py, float* __restrict__ feats) {
  int n = blockIdx.x, c = threadIdx.x;
  float fx = px[n], fy = py[n];
  float ix = fminf(fmaxf((fx + 1.f)*(IW*0.5f) - 0.5f, 0.f), (float)(IW-1));
  float iy = fminf(fmaxf((fy + 1.f)*(IH*0.5f) - 0.5f, 0.f), (float)(IH-1));
  float x0f = floorf(ix), y0f = floorf(iy);
  int xi0 = (int)x0f, yi0 = (int)y0f;
  int xi1 = min(xi0+1, IW-1), yi1 = min(yi0+1, IH-1);
  float wx = ix - x0f, wy = iy - y0f;
  int b = n / PPB;
  const float* xb = x + (size_t)(b*CIN + c)*(IH*IW);
  float v00 = xb[yi0*IW + xi0], v01 = xb[yi0*IW + xi1];
  float v10 = xb[yi1*IW + xi0], v11 = xb[yi1*IW + xi1];
  float top = v00 + (v01 - v00)*wx;
  float bot = v10 + (v11 - v10)*wx;
  feats[(size_t)n*CIN + c] = top + (bot - top)*wy;
}

// ---- all_w[n][k][a] = max(1 - dist/1.2, 0) ----
__global__ void k_w(const float* __restrict__ pxyz, const int* __restrict__ pknn,
                    const float* __restrict__ kp, float* __restrict__ wall) {
  __shared__ float wtmp[16*240];
  __shared__ float kpl[45];
  int tid = threadIdx.x;
  if (tid < 45) kpl[tid] = kp[tid];
  int lp = tid >> 4, a = tid & 15;
  int n = blockIdx.x*16 + lp;
  int g = pknn[n*NNB + a] + (n / PPB)*PPB;
  float dx = pxyz[g*3+0] - pxyz[n*3+0];
  float dy = pxyz[g*3+1] - pxyz[n*3+1];
  float dz = pxyz[g*3+2] - pxyz[n*3+2];
  __syncthreads();
  #pragma unroll
  for (int k = 0; k < KKP; ++k) {
    float ex = dx - kpl[k*3+0], ey = dy - kpl[k*3+1], ez = dz - kpl[k*3+2];
    float dist = sqrtf(ex*ex + ey*ey + ez*ez);
    wtmp[lp*240 + k*16 + a] = fmaxf(1.f - dist*KPINV, 0.f);
  }
  __syncthreads();
  float* dst = wall + (size_t)blockIdx.x*3840;
  for (int i = tid; i < 3840; i += 256) dst[i] = wtmp[i];
}

// ---- fused weighted-einsum + GEMM.  BM=64 points/block, all 256 outputs.
// thread tile 8x8: m = tr*8+i, d = tc*8+j.  K-dim = (cc 0..31 chunks of 8 ch) x (k 0..14)
__global__ __launch_bounds__(256) void k_main(const float* __restrict__ feats,
        const float* __restrict__ wall, const int* __restrict__ pknn,
        const float* __restrict__ kpw, float* __restrict__ out,
        float* __restrict__ sums) {
  __shared__ float nf[64*136];   // [m][a][c]: m*136 + a*8 + c   (34816 B)
  __shared__ float Ach[8*68];    // [c][m] stride 68             (2176 B)
  __shared__ float Wc[8*256];    // [c][d]                       (8192 B)
  int tid = threadIdx.x;
  int tr = tid >> 5, tc = tid & 31;
  int n0 = blockIdx.x*64;

  float acc[8][8];
  #pragma unroll
  for (int i = 0; i < 8; ++i)
    #pragma unroll
    for (int j = 0; j < 8; ++j) acc[i][j] = 0.f;

  // stage-1 assignment: m1 = tid>>2 (0..63), cp = tid&3 (c-pair)
  int m1 = tid >> 2, cp = tid & 3;
  const float* wrow = wall + (size_t)(n0 + m1)*240;

  for (int cc = 0; cc < 32; ++cc) {
    __syncthreads();   // nf safe to overwrite
    // gather neighbor feats for this channel chunk: 1024 rows x 8 floats
    #pragma unroll
    for (int it = 0; it < 8; ++it) {
      int e = tid + (it << 8);
      int row = e >> 1, h = e & 1;
      int m = row >> 4, a = row & 15;
      int n = n0 + m;
      int g = pknn[n*NNB + a] + (n / PPB)*PPB;
      float4 v = *(const float4*)(feats + (size_t)g*CIN + (cc << 3) + (h << 2));
      *(float4*)(nf + m*136 + (a << 3) + (h << 2)) = v;
    }
    for (int k = 0; k < KKP; ++k) {
      __syncthreads();   // k=0: nf ready; k>0: prev FMA done with Ach/Wc
      // load W chunk [k][cc*8..+8][0..256] into LDS
      #pragma unroll
      for (int ii = 0; ii < 2; ++ii) {
        int e = tid + (ii << 8);
        int c = e >> 6, dp = (e & 63) << 2;
        *(float4*)(Wc + (c << 8) + dp) =
            *(const float4*)(kpw + ((size_t)((k << 8) + (cc << 3) + c) << 8) + dp);
      }
      // compute A-chunk: Ach[c][m] = sum_a w[n,k,a] * nf[m][a][c]
      {
        float s0 = 0.f, s1 = 0.f;
        const float* wr = wrow + (k << 4);
        #pragma unroll
        for (int a = 0; a < 16; ++a) {
          float w = wr[a];
          float2 v = *(const float2*)(nf + m1*136 + (a << 3) + (cp << 1));
          s0 += w*v.x; s1 += w*v.y;
        }
        Ach[(cp << 1)*68 + m1]       = s0;
        Ach[((cp << 1) + 1)*68 + m1] = s1;
      }
      __syncthreads();   // Ach + Wc ready
      // 8x8 register-tile FMA over the 8 channels of this chunk
      #pragma unroll
      for (int c = 0; c < 8; ++c) {
        float4 a0 = *(const float4*)(Ach + c*68 + (tr << 3));
        float4 a1 = *(const float4*)(Ach + c*68 + (tr << 3) + 4);
        float4 b0 = *(const float4*)(Wc + (c << 8) + (tc << 3));
        float4 b1 = *(const float4*)(Wc + (c << 8) + (tc << 3) + 4);
        float av[8] = {a0.x,a0.y,a0.z,a0.w,a1.x,a1.y,a1.z,a1.w};
        float bv[8] = {b0.x,b0.y,b0.z,b0.w,b1.x,b1.y,b1.z,b1.w};
        #pragma unroll
        for (int i = 0; i < 8; ++i)
          #pragma unroll
          for (int j = 0; j < 8; ++j) acc[i][j] += av[i]*bv[j];
      }
    }
  }

  // ---- epilogue: store raw out + block-reduced BN partial sums ----
  __syncthreads();
  float ts[8], ts2[8];
  #pragma unroll
  for (int j = 0; j < 8; ++j) { ts[j] = 0.f; ts2[j] = 0.f; }
  #pragma unroll
  for (int i = 0; i < 8; ++i) {
    int n = n0 + (tr << 3) + i;
    float4 o0 = {acc[i][0], acc[i][1], acc[i][2], acc[i][3]};
    float4 o1 = {acc[i][4], acc[i][5], acc[i][6], acc[i][7]};
    *(float4*)(out + (size_t)n*COUT + (tc << 3))     = o0;
    *(float4*)(out + (size_t)n*COUT + (tc << 3) + 4) = o1;
    #pragma unroll
    for (int j = 0; j < 8; ++j) { float v = acc[i][j]; ts[j] += v; ts2[j] += v*v; }
  }
  float* red = nf;  // reuse: 8*256*2 = 4096 floats
  #pragma unroll
  for (int j = 0; j < 8; ++j) {
    red[tr*256 + (tc << 3) + j]        = ts[j];
    red[2048 + tr*256 + (tc << 3) + j] = ts2[j];
  }
  __syncthreads();
  {
    int d = tid;  // 0..255
    float s = 0.f, s2 = 0.f;
    #pragma unroll
    for (int r = 0; r < 8; ++r) { s += red[r*256 + d]; s2 += red[2048 + r*256 + d]; }
    atomicAdd(&sums[d], s);
    atomicAdd(&sums[256 + d], s2);
  }
}

__global__ void k_finalize(float* __restrict__ sums, const float* __restrict__ gamma,
                           const float* __restrict__ beta) {
  int d = threadIdx.x;
  float mean = sums[d] * (1.f/NPTS);
  float var  = sums[256 + d] * (1.f/NPTS) - mean*mean;
  float inv  = rsqrtf(var + 1e-5f);
  float sc   = inv * gamma[d];
  sums[512 + d] = sc;
  sums[768 + d] = beta[d] - mean*sc;
}

__global__ void k_bnrelu(float* __restrict__ out, const float* __restrict__ sums) {
  int idx = blockIdx.x*256 + threadIdx.x;       // float4 index
  int d = (idx << 2) & 255;
  float4 v  = *(float4*)(out + (size_t)idx*4);
  float4 sc = *(const float4*)(sums + 512 + d);
  float4 sh = *(const float4*)(sums + 768 + d);
  v.x = fmaxf(v.x*sc.x + sh.x, 0.f);
  v.y = fmaxf(v.y*sc.y + sh.y, 0.f);
  v.z = fmaxf(v.z*sc.z + sh.z, 0.f);
  v.w = fmaxf(v.w*sc.w + sh.w, 0.f);
  *(float4*)(out + (size_t)idx*4) = v;
}

extern "C" void kernel_launch(void* const* d_in, const int* in_sizes, int n_in,
                              void* d_out, int out_size, void* d_ws, size_t ws_size,
                              hipStream_t stream) {
  const float* x     = (const float*)d_in[0];
  const float* px    = (const float*)d_in[1];
  const float* py    = (const float*)d_in[2];
  const float* pxyz  = (const float*)d_in[3];
  const int*   pknn  = (const int*)d_in[4];
  // d_in[5] num_points: constant P per batch, folded into n/PPB
  const float* kp    = (const float*)d_in[6];
  const float* kpw   = (const float*)d_in[7];
  const float* gamma = (const float*)d_in[8];
  const float* beta  = (const float*)d_in[9];
  float* out = (float*)d_out;
  float* ws  = (float*)d_ws;
  float* feats = ws + WS_FEATS;
  float* wall  = ws + WS_WALL;
  float* sums  = ws + WS_SUMS;

  k_zero<<<2, 256, 0, stream>>>(sums);
  k_feats<<<NPTS, 256, 0, stream>>>(x, px, py, feats);
  k_w<<<NPTS/16, 256, 0, stream>>>(pxyz, pknn, kp, wall);
  k_main<<<NPTS/64, 256, 0, stream>>>(feats, wall, pknn, kpw, out, sums);
  k_finalize<<<1, 256, 0, stream>>>(sums, gamma, beta);
  k_bnrelu<<<NPTS*COUT/1024, 256, 0, stream>>>(out, sums);
}

// Round 2
// 1702.750 us; speedup vs baseline: 1.9106x; 1.9106x over previous
//
#include <hip/hip_runtime.h>

typedef unsigned short u16;
typedef unsigned int   u32;
typedef __attribute__((ext_vector_type(8))) short bf16x8;
typedef __attribute__((ext_vector_type(4))) float f32x4;

#define NPTS 40000
#define PPB  10000
#define CIN  256
#define COUT 256
#define KKP  15
#define NNB  16
#define IH   64
#define IW   2048
#define KPINV (1.0f/1.2f)
#define KDIM 3840   // 15 k * 256 c, k-major

// ---------- helpers ----------
__device__ __forceinline__ u16 f2bf(float x) {          // RNE float->bf16
  u32 u = __float_as_uint(x);
  u32 r = u + 0x7fffu + ((u >> 16) & 1u);
  return (u16)(r >> 16);
}
__device__ __forceinline__ float bf2f(u16 u) {
  return __uint_as_float(((u32)u) << 16);
}
__device__ __forceinline__ void unpack8(uint4 u, float* f) {
  f[0] = __uint_as_float(u.x << 16); f[1] = __uint_as_float(u.x & 0xffff0000u);
  f[2] = __uint_as_float(u.y << 16); f[3] = __uint_as_float(u.y & 0xffff0000u);
  f[4] = __uint_as_float(u.z << 16); f[5] = __uint_as_float(u.z & 0xffff0000u);
  f[6] = __uint_as_float(u.w << 16); f[7] = __uint_as_float(u.w & 0xffff0000u);
}
__device__ __forceinline__ u32 pack2(float a, float b) {
  return (u32)f2bf(a) | ((u32)f2bf(b) << 16);
}
__device__ __forceinline__ void gload16(const u16* g, u16* l) {
  __builtin_amdgcn_global_load_lds((const __attribute__((address_space(1))) void*)g,
                                   (__attribute__((address_space(3))) void*)l, 16, 0, 0);
}

__global__ void k_zero(float* __restrict__ p) {
  p[blockIdx.x*256 + threadIdx.x] = 0.f;
}

// ---------- transpose x [b][c][y][w] f32 -> xt [b][y][w][c] bf16 ----------
__global__ void k_tx(const float* __restrict__ x, u16* __restrict__ xt) {
  __shared__ float t[64*65];
  int bi = blockIdx.x;
  int w0 = (bi & 31) << 6;
  int c0 = ((bi >> 5) & 3) << 6;
  int y  = (bi >> 7) & 63;
  int b  = bi >> 13;
  int tid = threadIdx.x, l = tid & 63, q = tid >> 6;
  const float* src = x + ((size_t)(b*256 + c0)*64 + y)*2048 + w0;
  #pragma unroll
  for (int i = 0; i < 16; ++i) {
    int cl = i*4 + q;
    t[cl*65 + l] = src[(size_t)cl*131072 + l];
  }
  __syncthreads();
  u16* dst = xt + ((size_t)(b*64 + y)*2048 + w0)*256 + c0;
  #pragma unroll
  for (int i = 0; i < 16; ++i) {
    int wl = i*4 + q;
    dst[(size_t)wl*256 + l] = f2bf(t[l*65 + wl]);
  }
}

// ---------- bilinear from channel-last xt ----------
__global__ void k_feats2(const u16* __restrict__ xt, const float* __restrict__ px,
                         const float* __restrict__ py, u16* __restrict__ feats) {
  int n = blockIdx.x, c = threadIdx.x;
  float fx = px[n], fy = py[n];
  float ix = fminf(fmaxf((fx + 1.f)*(IW*0.5f) - 0.5f, 0.f), (float)(IW-1));
  float iy = fminf(fmaxf((fy + 1.f)*(IH*0.5f) - 0.5f, 0.f), (float)(IH-1));
  float x0f = floorf(ix), y0f = floorf(iy);
  int xi0 = (int)x0f, yi0 = (int)y0f;
  int xi1 = min(xi0+1, IW-1), yi1 = min(yi0+1, IH-1);
  float wx = ix - x0f, wy = iy - y0f;
  int b = n / PPB;
  const u16* base = xt + (size_t)b*64*2048*256;
  float v00 = bf2f(base[((size_t)yi0*2048 + xi0)*256 + c]);
  float v01 = bf2f(base[((size_t)yi0*2048 + xi1)*256 + c]);
  float v10 = bf2f(base[((size_t)yi1*2048 + xi0)*256 + c]);
  float v11 = bf2f(base[((size_t)yi1*2048 + xi1)*256 + c]);
  float top = v00 + (v01 - v00)*wx;
  float bot = v10 + (v11 - v10)*wx;
  feats[(size_t)n*256 + c] = f2bf(top + (bot - top)*wy);
}

// ---------- fallback: bilinear direct from channel-major x ----------
__global__ void k_featsd(const float* __restrict__ x, const float* __restrict__ px,
                         const float* __restrict__ py, u16* __restrict__ feats) {
  int n = blockIdx.x, c = threadIdx.x;
  float fx = px[n], fy = py[n];
  float ix = fminf(fmaxf((fx + 1.f)*(IW*0.5f) - 0.5f, 0.f), (float)(IW-1));
  float iy = fminf(fmaxf((fy + 1.f)*(IH*0.5f) - 0.5f, 0.f), (float)(IH-1));
  float x0f = floorf(ix), y0f = floorf(iy);
  int xi0 = (int)x0f, yi0 = (int)y0f;
  int xi1 = min(xi0+1, IW-1), yi1 = min(yi0+1, IH-1);
  float wx = ix - x0f, wy = iy - y0f;
  int b = n / PPB;
  const float* xb = x + (size_t)(b*CIN + c)*(IH*IW);
  float v00 = xb[yi0*IW + xi0], v01 = xb[yi0*IW + xi1];
  float v10 = xb[yi1*IW + xi0], v11 = xb[yi1*IW + xi1];
  float top = v00 + (v01 - v00)*wx;
  float bot = v10 + (v11 - v10)*wx;
  feats[(size_t)n*CIN + c] = f2bf(top + (bot - top)*wy);
}

// ---------- all_w[n][k][a] fp32 ----------
__global__ void k_w(const float* __restrict__ pxyz, const int* __restrict__ pknn,
                    const float* __restrict__ kp, float* __restrict__ wall) {
  __shared__ float wtmp[16*240];
  __shared__ float kpl[45];
  int tid = threadIdx.x;
  if (tid < 45) kpl[tid] = kp[tid];
  int lp = tid >> 4, a = tid & 15;
  int n = blockIdx.x*16 + lp;
  int g = pknn[n*NNB + a] + (n / PPB)*PPB;
  float dx = pxyz[g*3+0] - pxyz[n*3+0];
  float dy = pxyz[g*3+1] - pxyz[n*3+1];
  float dz = pxyz[g*3+2] - pxyz[n*3+2];
  __syncthreads();
  #pragma unroll
  for (int k = 0; k < KKP; ++k) {
    float ex = dx - kpl[k*3+0], ey = dy - kpl[k*3+1], ez = dz - kpl[k*3+2];
    float dist = sqrtf(ex*ex + ey*ey + ez*ez);
    wtmp[lp*240 + k*16 + a] = fmaxf(1.f - dist*KPINV, 0.f);
  }
  __syncthreads();
  float* dst = wall + (size_t)blockIdx.x*3840;
  for (int i = tid; i < 3840; i += 256) dst[i] = wtmp[i];
}

// ---------- transpose kpw [3840 kc][256 d] f32 -> Wt [256 d][3840 kc] bf16 ----------
__global__ void k_wt(const float* __restrict__ kpw, u16* __restrict__ Wt) {
  __shared__ float t[64*65];
  int kc0 = (blockIdx.x % 60) * 64;
  int d0  = (blockIdx.x / 60) * 64;
  int tid = threadIdx.x, l = tid & 63, q = tid >> 6;
  #pragma unroll
  for (int i = 0; i < 16; ++i) {
    int kcl = i*4 + q;
    t[kcl*65 + l] = kpw[(size_t)(kc0 + kcl)*256 + d0 + l];
  }
  __syncthreads();
  #pragma unroll
  for (int i = 0; i < 16; ++i) {
    int dl = i*4 + q;
    Wt[(size_t)(d0 + dl)*3840 + kc0 + l] = f2bf(t[l*65 + dl]);
  }
}

// ---------- stage 1: A[mlocal][k*256+c] bf16 = sum_a w[n][k][a] * feats[g(n,a)][c] ----------
// thread: m = tid>>2 (point in block), kq = tid&3 (k-quad). w in 64 VGPRs.
__global__ __launch_bounds__(256,2) void k_A(const u16* __restrict__ feats,
        const float* __restrict__ wall, const int* __restrict__ pknn,
        u16* __restrict__ A, int p0) {
  int tid = threadIdx.x;
  int m = tid >> 2, kq = tid & 3;
  int n = p0 + blockIdx.x*64 + m;
  int b = n / PPB;
  float w[4][16];
  const float* wr = wall + (size_t)n*240 + kq*64;   // k-major: kq*4 rows of 16, contiguous
  #pragma unroll
  for (int k4 = 0; k4 < 4; ++k4) {
    int k = kq*4 + k4;
    if (k < 15) {
      #pragma unroll
      for (int a = 0; a < 16; ++a) w[k4][a] = wr[k4*16 + a];
    } else {
      #pragma unroll
      for (int a = 0; a < 16; ++a) w[k4][a] = 0.f;
    }
  }
  const int* pk = pknn + (size_t)n*16;
  size_t goff[16];
  #pragma unroll
  for (int a = 0; a < 16; ++a) goff[a] = ((size_t)(pk[a] + b*PPB)) * 512;  // feats row bytes
  u16* Arow = A + (size_t)(blockIdx.x*64 + m)*KDIM;
  for (int cc = 0; cc < 32; ++cc) {
    float acc[4][8];
    #pragma unroll
    for (int k4 = 0; k4 < 4; ++k4)
      #pragma unroll
      for (int j = 0; j < 8; ++j) acc[k4][j] = 0.f;
    #pragma unroll
    for (int a = 0; a < 16; ++a) {
      uint4 u = *(const uint4*)((const char*)feats + goff[a] + cc*16);
      float f[8];
      unpack8(u, f);
      #pragma unroll
      for (int k4 = 0; k4 < 4; ++k4) {
        float wv = w[k4][a];
        #pragma unroll
        for (int j = 0; j < 8; ++j) acc[k4][j] += wv * f[j];
      }
    }
    #pragma unroll
    for (int k4 = 0; k4 < 4; ++k4) {
      int k = kq*4 + k4;
      if (k < 15) {
        uint4 st;
        st.x = pack2(acc[k4][0], acc[k4][1]);
        st.y = pack2(acc[k4][2], acc[k4][3]);
        st.z = pack2(acc[k4][4], acc[k4][5]);
        st.w = pack2(acc[k4][6], acc[k4][7]);
        *(uint4*)(Arow + k*256 + cc*8) = st;
      }
    }
  }
}

// ---------- stage 2: GEMM out[m][d] = sum_kc A[m][kc] * Wt[d][kc], bf16 MFMA ----------
// BM=64, BN=256, BK=64. 4 waves; wave wv owns d-range [wv*64, +64). 4x4 16x16 tiles/wave.
__global__ __launch_bounds__(256,2) void k_gemm(const u16* __restrict__ A,
        const u16* __restrict__ Wt, float* __restrict__ out, float* __restrict__ sums) {
  __shared__ __align__(16) u16 sA[64*64];
  __shared__ __align__(16) u16 sB[256*64];
  int tid = threadIdx.x;
  int wv = tid >> 6, ln = tid & 63;
  int m0 = blockIdx.x * 64;

  f32x4 acc[4][4];
  #pragma unroll
  for (int mt = 0; mt < 4; ++mt)
    #pragma unroll
    for (int nt = 0; nt < 4; ++nt) acc[mt][nt] = f32x4{0.f,0.f,0.f,0.f};

  // staging pointers: per round, idx = r*256+tid; row = idx>>3, 16B col = idx&7
  const u16* ag[2]; u16* al[2];
  #pragma unroll
  for (int r = 0; r < 2; ++r) {
    int idx = r*256 + tid;
    ag[r] = A + (size_t)(m0 + (idx >> 3))*KDIM + (idx & 7)*8;
    al[r] = sA + idx*8;
  }
  const u16* bg[8]; u16* bl[8];
  #pragma unroll
  for (int r = 0; r < 8; ++r) {
    int idx = r*256 + tid;
    bg[r] = Wt + (size_t)(idx >> 3)*KDIM + (idx & 7)*8;
    bl[r] = sB + idx*8;
  }
  // frag LDS element offsets
  int row = ln & 15, quad = ln >> 4;
  int aoff[4], boff[4];
  #pragma unroll
  for (int mt = 0; mt < 4; ++mt) aoff[mt] = (mt*16 + row)*64 + quad*8;
  #pragma unroll
  for (int nt = 0; nt < 4; ++nt) boff[nt] = (wv*64 + nt*16 + row)*64 + quad*8;

  for (int kt = 0; kt < 60; ++kt) {
    __syncthreads();
    #pragma unroll
    for (int r = 0; r < 2; ++r) gload16(ag[r] + kt*64, al[r]);
    #pragma unroll
    for (int r = 0; r < 8; ++r) gload16(bg[r] + kt*64, bl[r]);
    __syncthreads();
    #pragma unroll
    for (int ks = 0; ks < 2; ++ks) {
      bf16x8 af[4], bf[4];
      #pragma unroll
      for (int mt = 0; mt < 4; ++mt) af[mt] = *(const bf16x8*)(sA + aoff[mt] + ks*32);
      #pragma unroll
      for (int nt = 0; nt < 4; ++nt) bf[nt] = *(const bf16x8*)(sB + boff[nt] + ks*32);
      #pragma unroll
      for (int mt = 0; mt < 4; ++mt)
        #pragma unroll
        for (int nt = 0; nt < 4; ++nt)
          acc[mt][nt] = __builtin_amdgcn_mfma_f32_16x16x32_bf16(af[mt], bf[nt], acc[mt][nt], 0, 0, 0);
    }
  }

  // epilogue: C/D layout col = ln&15, row = quad*4 + r
  #pragma unroll
  for (int mt = 0; mt < 4; ++mt)
    #pragma unroll
    for (int nt = 0; nt < 4; ++nt) {
      int d = wv*64 + nt*16 + row;
      #pragma unroll
      for (int r = 0; r < 4; ++r) {
        int mm = m0 + mt*16 + quad*4 + r;
        out[(size_t)mm*COUT + d] = acc[mt][nt][r];
      }
    }
  // BN partial sums: reduce over the 16 rows this wave touches per d
  #pragma unroll
  for (int nt = 0; nt < 4; ++nt) {
    float s = 0.f, s2 = 0.f;
    #pragma unroll
    for (int mt = 0; mt < 4; ++mt)
      #pragma unroll
      for (int r = 0; r < 4; ++r) { float v = acc[mt][nt][r]; s += v; s2 += v*v; }
    s  += __shfl_xor(s, 16);  s  += __shfl_xor(s, 32);
    s2 += __shfl_xor(s2, 16); s2 += __shfl_xor(s2, 32);
    if (quad == 0) {
      int d = wv*64 + nt*16 + row;
      atomicAdd(&sums[d], s);
      atomicAdd(&sums[256 + d], s2);
    }
  }
}

__global__ void k_finalize(float* __restrict__ sums, const float* __restrict__ gamma,
                           const float* __restrict__ beta) {
  int d = threadIdx.x;
  float mean = sums[d] * (1.f/NPTS);
  float var  = sums[256 + d] * (1.f/NPTS) - mean*mean;
  float inv  = rsqrtf(var + 1e-5f);
  float sc   = inv * gamma[d];
  sums[512 + d] = sc;
  sums[768 + d] = beta[d] - mean*sc;
}

__global__ void k_bnrelu(float* __restrict__ out, const float* __restrict__ sums) {
  int idx = blockIdx.x*256 + threadIdx.x;
  int d = (idx << 2) & 255;
  float4 v  = *(float4*)(out + (size_t)idx*4);
  float4 sc = *(const float4*)(sums + 512 + d);
  float4 sh = *(const float4*)(sums + 768 + d);
  v.x = fmaxf(v.x*sc.x + sh.x, 0.f);
  v.y = fmaxf(v.y*sc.y + sh.y, 0.f);
  v.z = fmaxf(v.z*sc.z + sh.z, 0.f);
  v.w = fmaxf(v.w*sc.w + sh.w, 0.f);
  *(float4*)(out + (size_t)idx*4) = v;
}

extern "C" void kernel_launch(void* const* d_in, const int* in_sizes, int n_in,
                              void* d_out, int out_size, void* d_ws, size_t ws_size,
                              hipStream_t stream) {
  const float* x     = (const float*)d_in[0];
  const float* px    = (const float*)d_in[1];
  const float* py    = (const float*)d_in[2];
  const float* pxyz  = (const float*)d_in[3];
  const int*   pknn  = (const int*)d_in[4];
  const float* kp    = (const float*)d_in[6];
  const float* kpw   = (const float*)d_in[7];
  const float* gamma = (const float*)d_in[8];
  const float* beta  = (const float*)d_in[9];
  float* out = (float*)d_out;

  char* wsb = (char*)d_ws;
  size_t off = 0;
  auto take = [&](size_t bytes) { char* p = wsb + off; off = (off + bytes + 255) & ~(size_t)255; return p; };
  float* sums  = (float*)take(4096);
  u16*   Wt    = (u16*)take((size_t)256*KDIM*2);
  u16*   feats = (u16*)take((size_t)NPTS*256*2);
  float* wall  = (float*)take((size_t)NPTS*240*4);
  size_t fixed_off = off;

  const size_t xtB   = (size_t)4*64*2048*256*2;      // 268,435,456
  const size_t Afull = (size_t)NPTS*KDIM*2;          // 307,200,000
  const size_t A8k   = (size_t)8192*KDIM*2;          //  62,914,560
  bool use_xt; size_t chunkpts;
  if      (ws_size >= fixed_off + xtB + Afull + 1024) { use_xt = true;  chunkpts = NPTS; }
  else if (ws_size >= fixed_off + xtB + A8k  + 1024)  { use_xt = true;  chunkpts = 8192; }
  else if (ws_size >= fixed_off + Afull + 1024)       { use_xt = false; chunkpts = NPTS; }
  else if (ws_size >= fixed_off + A8k  + 1024)        { use_xt = false; chunkpts = 8192; }
  else                                                { use_xt = false; chunkpts = 2048; }
  u16* xt = use_xt ? (u16*)take(xtB) : nullptr;
  u16* Abuf = (u16*)take((size_t)chunkpts*KDIM*2);

  k_zero<<<4, 256, 0, stream>>>(sums);
  k_wt<<<240, 256, 0, stream>>>(kpw, Wt);
  k_w<<<NPTS/16, 256, 0, stream>>>(pxyz, pknn, kp, wall);
  if (use_xt) {
    k_tx<<<32768, 256, 0, stream>>>(x, xt);
    k_feats2<<<NPTS, 256, 0, stream>>>(xt, px, py, feats);
  } else {
    k_featsd<<<NPTS, 256, 0, stream>>>(x, px, py, feats);
  }
  for (int p0 = 0; p0 < NPTS; ) {
    int cnt = (int)chunkpts < (NPTS - p0) ? (int)chunkpts : (NPTS - p0);
    k_A<<<cnt/64, 256, 0, stream>>>(feats, wall, pknn, Abuf, p0);
    k_gemm<<<cnt/64, 256, 0, stream>>>(Abuf, Wt, out + (size_t)p0*COUT, sums);
    p0 += cnt;
  }
  k_finalize<<<1, 256, 0, stream>>>(sums, gamma, beta);
  k_bnrelu<<<NPTS*COUT/1024, 256, 0, stream>>>(out, sums);
}